// Round 5
// baseline (8336.088 us; speedup 1.0000x reference)
//
#include <hip/hip_runtime.h>
#include <cfloat>
#include <cmath>
#include <climits>

// Problem constants
#define N_ROWS   32768      // 32*1024
#define D_DIM    512
#define K_CODES  4096
#define KHALF    2048

// Main-kernel tiling
#define BN   128            // rows per block
#define BK   128            // codes per K-tile
#define BD   32             // depth per LDS stage
#define LSTR 140            // padded LDS row stride (floats)

#define EPS_GAP 0.005f      // fp32 top-2 gap below which we re-check via np-emulation

// Output layout (floats from start of d_out)
#define OUT_Q     0
#define OUT_LOSS  16777216
#define OUT_INDS  16777217
#define OUT_EMB   16809985
#define OUT_PERP  18907137

// Scratch layout (floats, relative to out_emb region; final emb copy overwrites)
#define E_NORM_OFF    0
#define X_NORM_OFF    4096
#define PMIN_OFF      36864
#define PIDX_OFF      102400
#define PSEC_OFF      167936
#define FIDX_OFF      233472
#define ROWPART_OFF   266240
#define HIST_OFF      299008
#define FLAGCNT_OFF   303104
#define FLAGLIST_OFF  303105

// BIJECTIVE swizzle: block b = x>>5 gets +4b floats.
__device__ __forceinline__ int swz(int x) { return x + (((x >> 5) & 3) << 2); }

// ---------------------------------------------------------------------------
// numpy fp32 pairwise-sum emulation (AVX512 path, GCC manylinux build):
//  - 128-block: 8 zmm vectors (16 lanes); vector tree ((r0+r1)+(r2+r3))+((r4+r5)+(r6+r7));
//    then _mm512_reduce_add_ps (GCC): fold dist 8, fold dist 4, then ((u0+u1)+u2)+u3.
//  - n=512: fl( fl(B0+B1) + fl(B2+B3) ).
// All ops via __fadd_rn/__fmul_rn to block FMA contraction.
// ---------------------------------------------------------------------------
__device__ __forceinline__ float np_block128_sq(const float* p) {
    float P[16];
    #pragma unroll
    for (int l = 0; l < 16; ++l) {
        float s0 = __fmul_rn(p[0 * 16 + l], p[0 * 16 + l]);
        float s1 = __fmul_rn(p[1 * 16 + l], p[1 * 16 + l]);
        float s2 = __fmul_rn(p[2 * 16 + l], p[2 * 16 + l]);
        float s3 = __fmul_rn(p[3 * 16 + l], p[3 * 16 + l]);
        float s4 = __fmul_rn(p[4 * 16 + l], p[4 * 16 + l]);
        float s5 = __fmul_rn(p[5 * 16 + l], p[5 * 16 + l]);
        float s6 = __fmul_rn(p[6 * 16 + l], p[6 * 16 + l]);
        float s7 = __fmul_rn(p[7 * 16 + l], p[7 * 16 + l]);
        float a01 = __fadd_rn(s0, s1);
        float a23 = __fadd_rn(s2, s3);
        float a45 = __fadd_rn(s4, s5);
        float a67 = __fadd_rn(s6, s7);
        P[l] = __fadd_rn(__fadd_rn(a01, a23), __fadd_rn(a45, a67));
    }
    float T3[8];
    #pragma unroll
    for (int k = 0; k < 8; ++k) T3[k] = __fadd_rn(P[k], P[k + 8]);   // dist 8
    float T6[4];
    #pragma unroll
    for (int k = 0; k < 4; ++k) T6[k] = __fadd_rn(T3[k], T3[k + 4]); // dist 4
    return __fadd_rn(__fadd_rn(__fadd_rn(T6[0], T6[1]), T6[2]), T6[3]); // sequential
}

__device__ __forceinline__ float np_sum512_sq(const float* p) {
    float B0 = np_block128_sq(p);
    float B1 = np_block128_sq(p + 128);
    float B2 = np_block128_sq(p + 256);
    float B3 = np_block128_sq(p + 384);
    return __fadd_rn(__fadd_rn(B0, B1), __fadd_rn(B2, B3));
}

// ---------------------------------------------------------------------------
// Kernel 0: row norms for emb (items 0..4095) and latents (items 4096..36863)
// (feeds the fp32 main argmin only; flagged rows are re-derived exactly)
// ---------------------------------------------------------------------------
__global__ void vq_norms(const float* __restrict__ lat, const float* __restrict__ emb,
                         float* __restrict__ e_norm, float* __restrict__ x_norm) {
    int item = blockIdx.x * 4 + (threadIdx.x >> 6);
    int lane = threadIdx.x & 63;
    const float* src = (item < K_CODES)
        ? (emb + (size_t)item * D_DIM)
        : (lat + (size_t)(item - K_CODES) * D_DIM);
    const float4* s4 = (const float4*)src;
    float4 a = s4[lane];
    float4 b = s4[64 + lane];
    float s = a.x * a.x + a.y * a.y + a.z * a.z + a.w * a.w
            + b.x * b.x + b.y * b.y + b.z * b.z + b.w * b.w;
    #pragma unroll
    for (int off = 32; off > 0; off >>= 1) s += __shfl_down(s, off);
    if (lane == 0) {
        if (item < K_CODES) e_norm[item] = s;
        else                x_norm[item - K_CODES] = s;
    }
}

// ---------------------------------------------------------------------------
// Kernel 1: tiled fp32 "GEMM + argmin" with second-best tracking.
// ---------------------------------------------------------------------------
__global__ __launch_bounds__(256, 2)
void vq_argmin(const float* __restrict__ A, const float* __restrict__ E,
               const float* __restrict__ e_norm, const float* __restrict__ x_norm,
               float* __restrict__ pmin, int* __restrict__ pidx,
               float* __restrict__ psec)
{
    __shared__ float As[BD][LSTR];
    __shared__ float Bs[BD][LSTR];

    const int tid = threadIdx.x;
    const int tr = tid >> 4;
    const int tc = tid & 15;
    const int row0  = blockIdx.x * BN;
    const int kbase = blockIdx.y * KHALF;

    const int sa = swz(8 * tr);
    const int sb = swz(8 * tc);

    float xn[8];
    #pragma unroll
    for (int j = 0; j < 8; ++j) xn[j] = x_norm[row0 + tr * 8 + j];

    float bestv[8], secv[8];
    int   besti[8];
    #pragma unroll
    for (int j = 0; j < 8; ++j) { bestv[j] = FLT_MAX; secv[j] = FLT_MAX; besti[j] = 0; }

    for (int kt = 0; kt < KHALF / BK; ++kt) {
        const int kc0 = kbase + kt * BK;

        float acc[8][8];
        #pragma unroll
        for (int j = 0; j < 8; ++j)
            #pragma unroll
            for (int l = 0; l < 8; ++l) acc[j][l] = 0.f;

        for (int dt = 0; dt < D_DIM / BD; ++dt) {
            const int d0 = dt * BD;
            __syncthreads();
            #pragma unroll
            for (int i = 0; i < 4; ++i) {
                int li = i * 256 + tid;
                int r  = li >> 3;
                int dp = (li & 7) << 2;
                const float4 av = *(const float4*)(A + (size_t)(row0 + r) * D_DIM + d0 + dp);
                const float4 bv = *(const float4*)(E + (size_t)(kc0  + r) * D_DIM + d0 + dp);
                int rs = swz(r);
                As[dp + 0][rs] = av.x; As[dp + 1][rs] = av.y;
                As[dp + 2][rs] = av.z; As[dp + 3][rs] = av.w;
                Bs[dp + 0][rs] = bv.x; Bs[dp + 1][rs] = bv.y;
                Bs[dp + 2][rs] = bv.z; Bs[dp + 3][rs] = bv.w;
            }
            __syncthreads();

            #pragma unroll 8
            for (int d = 0; d < BD; ++d) {
                const float4* ap = (const float4*)&As[d][sa];
                const float4* bp = (const float4*)&Bs[d][sb];
                float4 a0 = ap[0], a1 = ap[1];
                float4 b0 = bp[0], b1 = bp[1];
                float a[8] = {a0.x, a0.y, a0.z, a0.w, a1.x, a1.y, a1.z, a1.w};
                float b[8] = {b0.x, b0.y, b0.z, b0.w, b1.x, b1.y, b1.z, b1.w};
                #pragma unroll
                for (int j = 0; j < 8; ++j)
                    #pragma unroll
                    for (int l = 0; l < 8; ++l)
                        acc[j][l] += a[j] * b[l];
            }
        }

        #pragma unroll
        for (int j = 0; j < 8; ++j) {
            #pragma unroll
            for (int l = 0; l < 8; ++l) {
                int c = kc0 + tc * 8 + l;
                float dist = xn[j] + e_norm[c] - 2.f * acc[j][l];
                if (dist < bestv[j]) {
                    secv[j] = bestv[j]; bestv[j] = dist; besti[j] = c;
                } else if (dist < secv[j]) {
                    secv[j] = dist;
                }
            }
        }
    }

    #pragma unroll
    for (int j = 0; j < 8; ++j) {
        float v = bestv[j], s = secv[j];
        int idx = besti[j];
        #pragma unroll
        for (int off = 8; off > 0; off >>= 1) {
            float v2 = __shfl_xor(v, off);
            int   i2 = __shfl_xor(idx, off);
            float s2 = __shfl_xor(s, off);
            float ns = fminf(fminf(s, s2), fmaxf(v, v2));
            if (v2 < v || (v2 == v && i2 < idx)) { v = v2; idx = i2; }
            s = ns;
        }
        if (tc == 0) {
            int rg = row0 + tr * 8 + j;
            pmin[blockIdx.y * N_ROWS + rg] = v;
            pidx[blockIdx.y * N_ROWS + rg] = idx;
            psec[blockIdx.y * N_ROWS + rg] = s;
        }
    }
}

// ---------------------------------------------------------------------------
// Kernel 2: combine halves -> fidx; flag near-tied rows for np-exact recheck.
// ---------------------------------------------------------------------------
__global__ void vq_select(const float* __restrict__ pmin, const int* __restrict__ pidx,
                          const float* __restrict__ psec,
                          int* __restrict__ fidx, int* __restrict__ flagcnt,
                          int* __restrict__ flaglist) {
    int row = blockIdx.x * 256 + threadIdx.x;
    if (row >= N_ROWS) return;
    float v0 = pmin[row], v1 = pmin[N_ROWS + row];
    float s0 = psec[row], s1 = psec[N_ROWS + row];
    int   i0 = pidx[row], i1 = pidx[N_ROWS + row];

    float best = v0; int bi = i0;
    if (v1 < v0) { best = v1; bi = i1; }
    float sec = fminf(fminf(s0, s1), fmaxf(v0, v1));

    fidx[row] = bi;
    if (sec - best < EPS_GAP) {
        int p = atomicAdd(flagcnt, 1);
        flaglist[p] = row;
    }
}

// ---------------------------------------------------------------------------
// Kernel 3: BIT-EXACT numpy emulation for flagged rows.
//   t1 = np_pairwise_fp32(x*x)         (same tree as np.sum axis=-1, AVX512/GCC)
//   t2 = np_pairwise_fp32(e*e)
//   dot = sequential fp32 FMA over k=0..511 (OpenBLAS sgemm microkernel order)
//   d32 = fl32(fl32(t1+t2) - 2*dot); argmin, first-index tie-break.
// One block per flagged row (grid-stride); 16-code LDS tiles, 16 owner threads.
// ---------------------------------------------------------------------------
#define FIX_TC  16
#define FIX_STR 516   // pad: bank (4c+k)%32 -> 2-way only

__global__ void vq_fix(const float* __restrict__ lat, const float* __restrict__ emb,
                       const int* __restrict__ flagcnt, const int* __restrict__ flaglist,
                       int* __restrict__ fidx) {
    __shared__ float xs[D_DIM];
    __shared__ float es[FIX_TC][FIX_STR];
    __shared__ float bval[FIX_TC];
    __shared__ int   bidx[FIX_TC];

    const int t   = threadIdx.x;
    const int cnt = *flagcnt;

    for (int f = blockIdx.x; f < cnt; f += gridDim.x) {
        const int row = flaglist[f];
        __syncthreads();
        xs[t]       = lat[(size_t)row * D_DIM + t];
        xs[t + 256] = lat[(size_t)row * D_DIM + t + 256];
        __syncthreads();

        float t1 = 0.f;
        if (t < FIX_TC) t1 = np_sum512_sq(xs);

        float best = FLT_MAX;
        int   bi   = INT_MAX;

        for (int tile = 0; tile < K_CODES / FIX_TC; ++tile) {
            __syncthreads();   // protect es from previous tile's readers
            #pragma unroll
            for (int i = 0; i < 8; ++i) {
                int li = i * 256 + t;        // 0..2047 float4 slots
                int c  = li >> 7;            // 0..15
                int q  = li & 127;           // float4 pos in row
                float4 v = *(const float4*)(emb + (size_t)(tile * FIX_TC + c) * D_DIM + q * 4);
                float* dst = &es[c][q * 4];
                dst[0] = v.x; dst[1] = v.y; dst[2] = v.z; dst[3] = v.w;
            }
            __syncthreads();

            if (t < FIX_TC) {
                const float* e = es[t];
                float t2 = np_sum512_sq(e);
                float dot = 0.f;
                for (int k = 0; k < D_DIM; ++k)
                    dot = __fmaf_rn(xs[k], e[k], dot);     // sequential, BLAS order
                float d32 = __fsub_rn(__fadd_rn(t1, t2), __fmul_rn(2.0f, dot));
                int c = tile * FIX_TC + t;
                if (d32 < best) { best = d32; bi = c; }    // ascending -> first index
            }
        }

        if (t < FIX_TC) { bval[t] = best; bidx[t] = bi; }
        __syncthreads();
        if (t == 0) {
            float bv = bval[0]; int bx = bidx[0];
            #pragma unroll
            for (int w = 1; w < FIX_TC; ++w)
                if (bval[w] < bv || (bval[w] == bv && bidx[w] < bx)) {
                    bv = bval[w]; bx = bidx[w];
                }
            fidx[row] = bx;
        }
        __syncthreads();
    }
}

// ---------------------------------------------------------------------------
// Kernel 4: gather quantized rows, per-row MSE partial, histogram, inds.
// ---------------------------------------------------------------------------
__global__ void vq_gather(const float* __restrict__ lat, const float* __restrict__ emb,
                          const int* __restrict__ fidx,
                          float* __restrict__ out_q, float* __restrict__ out_inds,
                          float* __restrict__ rowpart, int* __restrict__ hist) {
    int row  = blockIdx.x * 4 + (threadIdx.x >> 6);
    int lane = threadIdx.x & 63;

    int idx = fidx[row];

    if (lane == 0) {
        out_inds[row] = (float)idx;
        atomicAdd(&hist[idx], 1);
    }

    const float4* e4 = (const float4*)(emb + (size_t)idx * D_DIM);
    const float4* x4 = (const float4*)(lat + (size_t)row * D_DIM);
    float4*       q4 = (float4*)(out_q + (size_t)row * D_DIM);

    float s = 0.f;
    #pragma unroll
    for (int i = 0; i < 2; ++i) {
        float4 e = e4[i * 64 + lane];
        float4 x = x4[i * 64 + lane];
        q4[i * 64 + lane] = e;
        float dx = e.x - x.x, dy = e.y - x.y, dz = e.z - x.z, dw = e.w - x.w;
        s += dx * dx + dy * dy + dz * dz + dw * dw;
    }
    #pragma unroll
    for (int off = 32; off > 0; off >>= 1) s += __shfl_down(s, off);
    if (lane == 0) rowpart[row] = s;
}

// ---------------------------------------------------------------------------
// Kernel 5: deterministic final reductions: vq_loss and perplexity.
// ---------------------------------------------------------------------------
__global__ void vq_finalize(const float* __restrict__ rowpart, const int* __restrict__ hist,
                            float* __restrict__ out_loss, float* __restrict__ out_perp) {
    __shared__ float sdata[256];
    int t = threadIdx.x;

    float s = 0.f;
    for (int i = t; i < N_ROWS; i += 256) s += rowpart[i];
    sdata[t] = s;
    __syncthreads();
    for (int st = 128; st > 0; st >>= 1) {
        if (t < st) sdata[t] += sdata[t + st];
        __syncthreads();
    }
    if (t == 0) {
        float mse = sdata[0] / ((float)N_ROWS * (float)D_DIM);
        out_loss[0] = 1.05f * mse;
    }
    __syncthreads();

    float p = 0.f;
    for (int i = t; i < K_CODES; i += 256) {
        float pr = (float)hist[i] / (float)N_ROWS;
        p += pr * logf(pr + 1e-10f);
    }
    sdata[t] = p;
    __syncthreads();
    for (int st = 128; st > 0; st >>= 1) {
        if (t < st) sdata[t] += sdata[t + st];
        __syncthreads();
    }
    if (t == 0) out_perp[0] = expf(-sdata[0]);
}

// ---------------------------------------------------------------------------
extern "C" void kernel_launch(void* const* d_in, const int* in_sizes, int n_in,
                              void* d_out, int out_size, void* d_ws, size_t ws_size,
                              hipStream_t stream) {
    const float* lat = (const float*)d_in[0];
    const float* emb = (const float*)d_in[1];
    float* out = (float*)d_out;

    float* out_q    = out + OUT_Q;
    float* out_loss = out + OUT_LOSS;
    float* out_inds = out + OUT_INDS;
    float* out_emb  = out + OUT_EMB;
    float* out_perp = out + OUT_PERP;

    float* sb       = out_emb;
    float* e_norm   = sb + E_NORM_OFF;
    float* x_norm   = sb + X_NORM_OFF;
    float* pmin     = sb + PMIN_OFF;
    int*   pidx     = (int*)(sb + PIDX_OFF);
    float* psec     = sb + PSEC_OFF;
    int*   fidx     = (int*)(sb + FIDX_OFF);
    float* rowpart  = sb + ROWPART_OFF;
    int*   hist     = (int*)(sb + HIST_OFF);
    int*   flagcnt  = (int*)(sb + FLAGCNT_OFF);
    int*   flaglist = (int*)(sb + FLAGLIST_OFF);

    hipMemsetAsync(hist, 0, (K_CODES + 1) * sizeof(int), stream);

    vq_norms<<<dim3(9216), dim3(256), 0, stream>>>(lat, emb, e_norm, x_norm);

    dim3 grid(N_ROWS / BN, 2);
    vq_argmin<<<grid, dim3(256), 0, stream>>>(lat, emb, e_norm, x_norm, pmin, pidx, psec);

    vq_select<<<dim3(N_ROWS / 256), dim3(256), 0, stream>>>(pmin, pidx, psec,
                                                            fidx, flagcnt, flaglist);

    vq_fix<<<dim3(256), dim3(256), 0, stream>>>(lat, emb, flagcnt, flaglist, fidx);

    vq_gather<<<dim3(N_ROWS / 4), dim3(256), 0, stream>>>(lat, emb, fidx,
                                                          out_q, out_inds, rowpart, hist);

    vq_finalize<<<dim3(1), dim3(256), 0, stream>>>(rowpart, hist, out_loss, out_perp);

    hipMemcpyAsync(out_emb, emb, (size_t)K_CODES * D_DIM * sizeof(float),
                   hipMemcpyDeviceToDevice, stream);
}

// Round 6
// 2414.139 us; speedup vs baseline: 3.4530x; 3.4530x over previous
//
#include <hip/hip_runtime.h>
#include <cfloat>
#include <cmath>
#include <climits>

// Problem constants
#define N_ROWS   32768      // 32*1024
#define D_DIM    512
#define K_CODES  4096
#define KHALF    2048

// Main-kernel tiling
#define BN   128            // rows per block
#define BK   128            // codes per K-tile
#define BD   32             // depth per LDS stage
#define LSTR 140            // padded LDS row stride (floats)

#define EPS_GAP  0.005f     // fp32 top-2 gap below which we re-check via np-emulation
#define EPS_CAND 0.05       // fp64 window that provably contains the np-argmin

// Output layout (floats from start of d_out)
#define OUT_Q     0
#define OUT_LOSS  16777216
#define OUT_INDS  16777217
#define OUT_EMB   16809985
#define OUT_PERP  18907137

// Scratch layout (floats, relative to out_emb region; final emb copy overwrites)
#define E_NORM_OFF    0
#define X_NORM_OFF    4096
#define PMIN_OFF      36864
#define PIDX_OFF      102400
#define PSEC_OFF      167936
#define FIDX_OFF      233472
#define ROWPART_OFF   266240
#define HIST_OFF      299008
#define FLAGCNT_OFF   303104
#define FLAGLIST_OFF  303105

// BIJECTIVE swizzle: block b = x>>5 gets +4b floats.
__device__ __forceinline__ int swz(int x) { return x + (((x >> 5) & 3) << 2); }

// ---------------------------------------------------------------------------
// numpy fp32 pairwise-sum emulation (AVX512 path, GCC manylinux build):
//  - 128-block: 8 zmm vectors (16 lanes); vector tree ((r0+r1)+(r2+r3))+((r4+r5)+(r6+r7));
//    then _mm512_reduce_add_ps (GCC): fold dist 8, fold dist 4, then ((u0+u1)+u2)+u3.
//  - n=512: fl( fl(B0+B1) + fl(B2+B3) ).
// All ops via __fadd_rn/__fmul_rn to block FMA contraction.
// ---------------------------------------------------------------------------
__device__ __forceinline__ float np_block128_sq(const float* p) {
    float P[16];
    #pragma unroll
    for (int l = 0; l < 16; ++l) {
        float s0 = __fmul_rn(p[0 * 16 + l], p[0 * 16 + l]);
        float s1 = __fmul_rn(p[1 * 16 + l], p[1 * 16 + l]);
        float s2 = __fmul_rn(p[2 * 16 + l], p[2 * 16 + l]);
        float s3 = __fmul_rn(p[3 * 16 + l], p[3 * 16 + l]);
        float s4 = __fmul_rn(p[4 * 16 + l], p[4 * 16 + l]);
        float s5 = __fmul_rn(p[5 * 16 + l], p[5 * 16 + l]);
        float s6 = __fmul_rn(p[6 * 16 + l], p[6 * 16 + l]);
        float s7 = __fmul_rn(p[7 * 16 + l], p[7 * 16 + l]);
        float a01 = __fadd_rn(s0, s1);
        float a23 = __fadd_rn(s2, s3);
        float a45 = __fadd_rn(s4, s5);
        float a67 = __fadd_rn(s6, s7);
        P[l] = __fadd_rn(__fadd_rn(a01, a23), __fadd_rn(a45, a67));
    }
    float T3[8];
    #pragma unroll
    for (int k = 0; k < 8; ++k) T3[k] = __fadd_rn(P[k], P[k + 8]);   // dist 8
    float T6[4];
    #pragma unroll
    for (int k = 0; k < 4; ++k) T6[k] = __fadd_rn(T3[k], T3[k + 4]); // dist 4
    return __fadd_rn(__fadd_rn(__fadd_rn(T6[0], T6[1]), T6[2]), T6[3]); // sequential
}

__device__ __forceinline__ float np_sum512_sq(const float* p) {
    float B0 = np_block128_sq(p);
    float B1 = np_block128_sq(p + 128);
    float B2 = np_block128_sq(p + 256);
    float B3 = np_block128_sq(p + 384);
    return __fadd_rn(__fadd_rn(B0, B1), __fadd_rn(B2, B3));
}

// ---------------------------------------------------------------------------
// Kernel 0: row norms for emb (items 0..4095) and latents (items 4096..36863)
// ---------------------------------------------------------------------------
__global__ void vq_norms(const float* __restrict__ lat, const float* __restrict__ emb,
                         float* __restrict__ e_norm, float* __restrict__ x_norm) {
    int item = blockIdx.x * 4 + (threadIdx.x >> 6);
    int lane = threadIdx.x & 63;
    const float* src = (item < K_CODES)
        ? (emb + (size_t)item * D_DIM)
        : (lat + (size_t)(item - K_CODES) * D_DIM);
    const float4* s4 = (const float4*)src;
    float4 a = s4[lane];
    float4 b = s4[64 + lane];
    float s = a.x * a.x + a.y * a.y + a.z * a.z + a.w * a.w
            + b.x * b.x + b.y * b.y + b.z * b.z + b.w * b.w;
    #pragma unroll
    for (int off = 32; off > 0; off >>= 1) s += __shfl_down(s, off);
    if (lane == 0) {
        if (item < K_CODES) e_norm[item] = s;
        else                x_norm[item - K_CODES] = s;
    }
}

// ---------------------------------------------------------------------------
// Kernel 1: tiled fp32 "GEMM + argmin" with second-best tracking.
// ---------------------------------------------------------------------------
__global__ __launch_bounds__(256, 2)
void vq_argmin(const float* __restrict__ A, const float* __restrict__ E,
               const float* __restrict__ e_norm, const float* __restrict__ x_norm,
               float* __restrict__ pmin, int* __restrict__ pidx,
               float* __restrict__ psec)
{
    __shared__ float As[BD][LSTR];
    __shared__ float Bs[BD][LSTR];

    const int tid = threadIdx.x;
    const int tr = tid >> 4;
    const int tc = tid & 15;
    const int row0  = blockIdx.x * BN;
    const int kbase = blockIdx.y * KHALF;

    const int sa = swz(8 * tr);
    const int sb = swz(8 * tc);

    float xn[8];
    #pragma unroll
    for (int j = 0; j < 8; ++j) xn[j] = x_norm[row0 + tr * 8 + j];

    float bestv[8], secv[8];
    int   besti[8];
    #pragma unroll
    for (int j = 0; j < 8; ++j) { bestv[j] = FLT_MAX; secv[j] = FLT_MAX; besti[j] = 0; }

    for (int kt = 0; kt < KHALF / BK; ++kt) {
        const int kc0 = kbase + kt * BK;

        float acc[8][8];
        #pragma unroll
        for (int j = 0; j < 8; ++j)
            #pragma unroll
            for (int l = 0; l < 8; ++l) acc[j][l] = 0.f;

        for (int dt = 0; dt < D_DIM / BD; ++dt) {
            const int d0 = dt * BD;
            __syncthreads();
            #pragma unroll
            for (int i = 0; i < 4; ++i) {
                int li = i * 256 + tid;
                int r  = li >> 3;
                int dp = (li & 7) << 2;
                const float4 av = *(const float4*)(A + (size_t)(row0 + r) * D_DIM + d0 + dp);
                const float4 bv = *(const float4*)(E + (size_t)(kc0  + r) * D_DIM + d0 + dp);
                int rs = swz(r);
                As[dp + 0][rs] = av.x; As[dp + 1][rs] = av.y;
                As[dp + 2][rs] = av.z; As[dp + 3][rs] = av.w;
                Bs[dp + 0][rs] = bv.x; Bs[dp + 1][rs] = bv.y;
                Bs[dp + 2][rs] = bv.z; Bs[dp + 3][rs] = bv.w;
            }
            __syncthreads();

            #pragma unroll 8
            for (int d = 0; d < BD; ++d) {
                const float4* ap = (const float4*)&As[d][sa];
                const float4* bp = (const float4*)&Bs[d][sb];
                float4 a0 = ap[0], a1 = ap[1];
                float4 b0 = bp[0], b1 = bp[1];
                float a[8] = {a0.x, a0.y, a0.z, a0.w, a1.x, a1.y, a1.z, a1.w};
                float b[8] = {b0.x, b0.y, b0.z, b0.w, b1.x, b1.y, b1.z, b1.w};
                #pragma unroll
                for (int j = 0; j < 8; ++j)
                    #pragma unroll
                    for (int l = 0; l < 8; ++l)
                        acc[j][l] += a[j] * b[l];
            }
        }

        #pragma unroll
        for (int j = 0; j < 8; ++j) {
            #pragma unroll
            for (int l = 0; l < 8; ++l) {
                int c = kc0 + tc * 8 + l;
                float dist = xn[j] + e_norm[c] - 2.f * acc[j][l];
                if (dist < bestv[j]) {
                    secv[j] = bestv[j]; bestv[j] = dist; besti[j] = c;
                } else if (dist < secv[j]) {
                    secv[j] = dist;
                }
            }
        }
    }

    #pragma unroll
    for (int j = 0; j < 8; ++j) {
        float v = bestv[j], s = secv[j];
        int idx = besti[j];
        #pragma unroll
        for (int off = 8; off > 0; off >>= 1) {
            float v2 = __shfl_xor(v, off);
            int   i2 = __shfl_xor(idx, off);
            float s2 = __shfl_xor(s, off);
            float ns = fminf(fminf(s, s2), fmaxf(v, v2));
            if (v2 < v || (v2 == v && i2 < idx)) { v = v2; idx = i2; }
            s = ns;
        }
        if (tc == 0) {
            int rg = row0 + tr * 8 + j;
            pmin[blockIdx.y * N_ROWS + rg] = v;
            pidx[blockIdx.y * N_ROWS + rg] = idx;
            psec[blockIdx.y * N_ROWS + rg] = s;
        }
    }
}

// ---------------------------------------------------------------------------
// Kernel 2: combine halves -> fidx; flag near-tied rows for np-exact recheck.
// ---------------------------------------------------------------------------
__global__ void vq_select(const float* __restrict__ pmin, const int* __restrict__ pidx,
                          const float* __restrict__ psec,
                          int* __restrict__ fidx, int* __restrict__ flagcnt,
                          int* __restrict__ flaglist) {
    int row = blockIdx.x * 256 + threadIdx.x;
    if (row >= N_ROWS) return;
    float v0 = pmin[row], v1 = pmin[N_ROWS + row];
    float s0 = psec[row], s1 = psec[N_ROWS + row];
    int   i0 = pidx[row], i1 = pidx[N_ROWS + row];

    float best = v0; int bi = i0;
    if (v1 < v0) { best = v1; bi = i1; }
    float sec = fminf(fminf(s0, s1), fmaxf(v0, v1));

    fidx[row] = bi;
    if (sec - best < EPS_GAP) {
        int p = atomicAdd(flagcnt, 1);
        flaglist[p] = row;
    }
}

// ---------------------------------------------------------------------------
// Kernel 3 (rewritten): flagged-row resolve.
//  Phase 1: fp64 distances for all 4096 codes, wave-per-code (coalesced,
//           parallel) -> dall[] in LDS + global fp64 min.
//  Phase 2: candidates = { c : d64[c] < d64min + EPS_CAND }.  EPS_CAND=0.05
//           exceeds 2x the worst-case 512-term fp32 accumulation error
//           (~0.016), so the np-argmin is provably a candidate.
//  Phase 3: bit-exact numpy emulation (pairwise-tree norms + sequential
//           sgemm FMA dot) on candidates only; lexicographic (d32, idx) min.
// 512 threads (8 waves); grid-stride over flagged rows.
// ---------------------------------------------------------------------------
#define FIX_THREADS 512
#define MAX_CAND    256

__global__ __launch_bounds__(FIX_THREADS)
void vq_fix(const float* __restrict__ lat, const float* __restrict__ emb,
            const int* __restrict__ flagcnt, const int* __restrict__ flaglist,
            int* __restrict__ fidx) {
    __shared__ float  xs[D_DIM];
    __shared__ float  dall[K_CODES];     // 16 KB
    __shared__ double wmin[8];
    __shared__ int    candcnt;
    __shared__ int    cands[MAX_CAND];
    __shared__ float  cd32[MAX_CAND];

    const int t    = threadIdx.x;
    const int wave = t >> 6;
    const int lane = t & 63;
    const int cnt  = *flagcnt;

    for (int f = blockIdx.x; f < cnt; f += gridDim.x) {
        const int row = flaglist[f];
        __syncthreads();   // protect all LDS reuse across row iterations
        xs[t] = lat[(size_t)row * D_DIM + t];   // 512 threads == D_DIM
        if (t == 0) candcnt = 0;
        __syncthreads();

        // ---- Phase 1: fp64 distances, wave per code ----
        double xa[8];
        #pragma unroll
        for (int j = 0; j < 8; ++j) xa[j] = (double)xs[lane * 8 + j];

        double lmin = DBL_MAX;
        for (int c = wave; c < K_CODES; c += 8) {
            const float4* e4 = (const float4*)(emb + (size_t)c * D_DIM);
            float4 ea = e4[lane * 2];
            float4 eb = e4[lane * 2 + 1];
            double s = 0.0;
            double d0 = xa[0] - (double)ea.x; s = fma(d0, d0, s);
            double d1 = xa[1] - (double)ea.y; s = fma(d1, d1, s);
            double d2 = xa[2] - (double)ea.z; s = fma(d2, d2, s);
            double d3 = xa[3] - (double)ea.w; s = fma(d3, d3, s);
            double d4 = xa[4] - (double)eb.x; s = fma(d4, d4, s);
            double d5 = xa[5] - (double)eb.y; s = fma(d5, d5, s);
            double d6 = xa[6] - (double)eb.z; s = fma(d6, d6, s);
            double d7 = xa[7] - (double)eb.w; s = fma(d7, d7, s);
            #pragma unroll
            for (int off = 32; off > 0; off >>= 1) s += __shfl_xor(s, off);
            if (lane == 0) dall[c] = (float)s;
            lmin = fmin(lmin, s);
        }
        if (lane == 0) wmin[wave] = lmin;
        __syncthreads();

        // ---- Phase 2: candidate collection ----
        double g = wmin[0];
        #pragma unroll
        for (int w = 1; w < 8; ++w) g = fmin(g, wmin[w]);
        const float thr = (float)(g + EPS_CAND);

        for (int c = t; c < K_CODES; c += FIX_THREADS) {
            if (dall[c] < thr) {
                int p = atomicAdd(&candcnt, 1);
                if (p < MAX_CAND) cands[p] = c;
            }
        }
        __syncthreads();

        // ---- Phase 3: bit-exact np eval on candidates ----
        int nc = candcnt < MAX_CAND ? candcnt : MAX_CAND;
        if (t < nc) {
            int c = cands[t];
            const float* e = emb + (size_t)c * D_DIM;
            float t1 = np_sum512_sq(xs);
            float t2 = np_sum512_sq(e);
            float dot = 0.f;
            for (int k = 0; k < D_DIM; ++k)
                dot = __fmaf_rn(xs[k], e[k], dot);     // sequential, BLAS order
            cd32[t] = __fsub_rn(__fadd_rn(t1, t2), __fmul_rn(2.0f, dot));
        }
        __syncthreads();

        if (t == 0) {
            float bv = cd32[0]; int bx = cands[0];
            for (int w = 1; w < nc; ++w) {
                if (cd32[w] < bv || (cd32[w] == bv && cands[w] < bx)) {
                    bv = cd32[w]; bx = cands[w];
                }
            }
            fidx[row] = bx;
        }
    }
}

// ---------------------------------------------------------------------------
// Kernel 4: gather quantized rows, per-row MSE partial, histogram, inds.
// ---------------------------------------------------------------------------
__global__ void vq_gather(const float* __restrict__ lat, const float* __restrict__ emb,
                          const int* __restrict__ fidx,
                          float* __restrict__ out_q, float* __restrict__ out_inds,
                          float* __restrict__ rowpart, int* __restrict__ hist) {
    int row  = blockIdx.x * 4 + (threadIdx.x >> 6);
    int lane = threadIdx.x & 63;

    int idx = fidx[row];

    if (lane == 0) {
        out_inds[row] = (float)idx;
        atomicAdd(&hist[idx], 1);
    }

    const float4* e4 = (const float4*)(emb + (size_t)idx * D_DIM);
    const float4* x4 = (const float4*)(lat + (size_t)row * D_DIM);
    float4*       q4 = (float4*)(out_q + (size_t)row * D_DIM);

    float s = 0.f;
    #pragma unroll
    for (int i = 0; i < 2; ++i) {
        float4 e = e4[i * 64 + lane];
        float4 x = x4[i * 64 + lane];
        q4[i * 64 + lane] = e;
        float dx = e.x - x.x, dy = e.y - x.y, dz = e.z - x.z, dw = e.w - x.w;
        s += dx * dx + dy * dy + dz * dz + dw * dw;
    }
    #pragma unroll
    for (int off = 32; off > 0; off >>= 1) s += __shfl_down(s, off);
    if (lane == 0) rowpart[row] = s;
}

// ---------------------------------------------------------------------------
// Kernel 5: deterministic final reductions: vq_loss and perplexity.
// ---------------------------------------------------------------------------
__global__ void vq_finalize(const float* __restrict__ rowpart, const int* __restrict__ hist,
                            float* __restrict__ out_loss, float* __restrict__ out_perp) {
    __shared__ float sdata[256];
    int t = threadIdx.x;

    float s = 0.f;
    for (int i = t; i < N_ROWS; i += 256) s += rowpart[i];
    sdata[t] = s;
    __syncthreads();
    for (int st = 128; st > 0; st >>= 1) {
        if (t < st) sdata[t] += sdata[t + st];
        __syncthreads();
    }
    if (t == 0) {
        float mse = sdata[0] / ((float)N_ROWS * (float)D_DIM);
        out_loss[0] = 1.05f * mse;
    }
    __syncthreads();

    float p = 0.f;
    for (int i = t; i < K_CODES; i += 256) {
        float pr = (float)hist[i] / (float)N_ROWS;
        p += pr * logf(pr + 1e-10f);
    }
    sdata[t] = p;
    __syncthreads();
    for (int st = 128; st > 0; st >>= 1) {
        if (t < st) sdata[t] += sdata[t + st];
        __syncthreads();
    }
    if (t == 0) out_perp[0] = expf(-sdata[0]);
}

// ---------------------------------------------------------------------------
extern "C" void kernel_launch(void* const* d_in, const int* in_sizes, int n_in,
                              void* d_out, int out_size, void* d_ws, size_t ws_size,
                              hipStream_t stream) {
    const float* lat = (const float*)d_in[0];
    const float* emb = (const float*)d_in[1];
    float* out = (float*)d_out;

    float* out_q    = out + OUT_Q;
    float* out_loss = out + OUT_LOSS;
    float* out_inds = out + OUT_INDS;
    float* out_emb  = out + OUT_EMB;
    float* out_perp = out + OUT_PERP;

    float* sb       = out_emb;
    float* e_norm   = sb + E_NORM_OFF;
    float* x_norm   = sb + X_NORM_OFF;
    float* pmin     = sb + PMIN_OFF;
    int*   pidx     = (int*)(sb + PIDX_OFF);
    float* psec     = sb + PSEC_OFF;
    int*   fidx     = (int*)(sb + FIDX_OFF);
    float* rowpart  = sb + ROWPART_OFF;
    int*   hist     = (int*)(sb + HIST_OFF);
    int*   flagcnt  = (int*)(sb + FLAGCNT_OFF);
    int*   flaglist = (int*)(sb + FLAGLIST_OFF);

    hipMemsetAsync(hist, 0, (K_CODES + 1) * sizeof(int), stream);

    vq_norms<<<dim3(9216), dim3(256), 0, stream>>>(lat, emb, e_norm, x_norm);

    dim3 grid(N_ROWS / BN, 2);
    vq_argmin<<<grid, dim3(256), 0, stream>>>(lat, emb, e_norm, x_norm, pmin, pidx, psec);

    vq_select<<<dim3(N_ROWS / 256), dim3(256), 0, stream>>>(pmin, pidx, psec,
                                                            fidx, flagcnt, flaglist);

    vq_fix<<<dim3(1024), dim3(FIX_THREADS), 0, stream>>>(lat, emb, flagcnt, flaglist, fidx);

    vq_gather<<<dim3(N_ROWS / 4), dim3(256), 0, stream>>>(lat, emb, fidx,
                                                          out_q, out_inds, rowpart, hist);

    vq_finalize<<<dim3(1), dim3(256), 0, stream>>>(rowpart, hist, out_loss, out_perp);

    hipMemcpyAsync(out_emb, emb, (size_t)K_CODES * D_DIM * sizeof(float),
                   hipMemcpyDeviceToDevice, stream);
}

// Round 8
// 2250.873 us; speedup vs baseline: 3.7035x; 1.0725x over previous
//
#include <hip/hip_runtime.h>
#include <cfloat>
#include <cmath>
#include <climits>
#include <cstdint>

// Problem constants
#define N_ROWS   32768
#define D_DIM    512
#define K_CODES  4096

#define EPS_GAP  0.008f     // MFMA-path gap below which we re-check via np-emulation
#define EPS_CAND 0.05       // fp64 window that provably contains the np-argmin
#define FLAG_CAP 12000

typedef short s16x8 __attribute__((ext_vector_type(8)));
typedef float f32x4 __attribute__((ext_vector_type(4)));

// ---------------------------------------------------------------------------
// Flat scratch layout in d_out (float indices).
//   emb_hi  [0, 1048576)           bf16 bits (4096x512 shorts)
//   emb_lo  [1048576, 2097152)
//   lat_hi  [2097152, 10485760)    (32768x512 shorts)
//   lat_lo  [10485760, 18874368)
//   e_norm  [18874368, 18878464)   -- clean tail (no overlap with splits)
//   flagcnt [18878464]
//   flaglist[18878465, 18890465)
//   fidx    u16 at [18890496, 18906880)
//   hist    [16777220, 16781316)   INSIDE lat_lo span -> must be zeroed only
//                                  AFTER vq_argmin_mfma (lat_lo dead)!
//   rowpart [16781316, 16814084)   (same zone; fully written post-argmin)
// Outputs: out_q [0,16777216) loss[16777216] inds[16777217,16809985)
//          emb  [16809985,18907137) perp[18907137]
// ---------------------------------------------------------------------------

__device__ __forceinline__ short f2bf_rne(float x) {
    unsigned u = __float_as_uint(x);
    unsigned r = (u + 0x7fffu + ((u >> 16) & 1u)) >> 16;
    return (short)r;
}
__device__ __forceinline__ float bf2f(short b) {
    return __uint_as_float(((unsigned)(unsigned short)b) << 16);
}

__device__ __forceinline__ void gld16(const short* g, short* l) {
    __builtin_amdgcn_global_load_lds(
        reinterpret_cast<const __attribute__((address_space(1))) unsigned int*>(
            reinterpret_cast<uintptr_t>(g)),
        reinterpret_cast<__attribute__((address_space(3))) unsigned int*>(
            (unsigned int)(reinterpret_cast<uintptr_t>(l))),
        16, 0, 0);
}

// ---------------------------------------------------------------------------
// numpy fp32 pairwise-sum emulation (AVX512/GCC path) -- unchanged, proven.
// ---------------------------------------------------------------------------
__device__ __forceinline__ float np_block128_sq(const float* p) {
    float P[16];
    #pragma unroll
    for (int l = 0; l < 16; ++l) {
        float s0 = __fmul_rn(p[0 * 16 + l], p[0 * 16 + l]);
        float s1 = __fmul_rn(p[1 * 16 + l], p[1 * 16 + l]);
        float s2 = __fmul_rn(p[2 * 16 + l], p[2 * 16 + l]);
        float s3 = __fmul_rn(p[3 * 16 + l], p[3 * 16 + l]);
        float s4 = __fmul_rn(p[4 * 16 + l], p[4 * 16 + l]);
        float s5 = __fmul_rn(p[5 * 16 + l], p[5 * 16 + l]);
        float s6 = __fmul_rn(p[6 * 16 + l], p[6 * 16 + l]);
        float s7 = __fmul_rn(p[7 * 16 + l], p[7 * 16 + l]);
        float a01 = __fadd_rn(s0, s1);
        float a23 = __fadd_rn(s2, s3);
        float a45 = __fadd_rn(s4, s5);
        float a67 = __fadd_rn(s6, s7);
        P[l] = __fadd_rn(__fadd_rn(a01, a23), __fadd_rn(a45, a67));
    }
    float T3[8];
    #pragma unroll
    for (int k = 0; k < 8; ++k) T3[k] = __fadd_rn(P[k], P[k + 8]);
    float T6[4];
    #pragma unroll
    for (int k = 0; k < 4; ++k) T6[k] = __fadd_rn(T3[k], T3[k + 4]);
    return __fadd_rn(__fadd_rn(__fadd_rn(T6[0], T6[1]), T6[2]), T6[3]);
}
__device__ __forceinline__ float np_sum512_sq(const float* p) {
    float B0 = np_block128_sq(p);
    float B1 = np_block128_sq(p + 128);
    float B2 = np_block128_sq(p + 256);
    float B3 = np_block128_sq(p + 384);
    return __fadd_rn(__fadd_rn(B0, B1), __fadd_rn(B2, B3));
}

// ---------------------------------------------------------------------------
// Kernel 0: split fp32 -> bf16 hi/lo for lat and emb.  8 elems per thread.
// ---------------------------------------------------------------------------
__global__ void vq_convert(const float* __restrict__ lat, const float* __restrict__ emb,
                           short* __restrict__ lat_hi, short* __restrict__ lat_lo,
                           short* __restrict__ emb_hi, short* __restrict__ emb_lo) {
    int i = blockIdx.x * 256 + threadIdx.x;   // octet index, 2359296 total
    const float* src; short *dh, *dl; size_t base;
    if (i < 2097152) { src = lat; dh = lat_hi; dl = lat_lo; base = (size_t)i * 8; }
    else             { src = emb; dh = emb_hi; dl = emb_lo; base = (size_t)(i - 2097152) * 8; }
    float4 a = *(const float4*)(src + base);
    float4 b = *(const float4*)(src + base + 4);
    float x[8] = {a.x, a.y, a.z, a.w, b.x, b.y, b.z, b.w};
    s16x8 hv, lv;
    #pragma unroll
    for (int j = 0; j < 8; ++j) {
        short h = f2bf_rne(x[j]);
        hv[j] = h;
        lv[j] = f2bf_rne(x[j] - bf2f(h));
    }
    *(s16x8*)(dh + base) = hv;
    *(s16x8*)(dl + base) = lv;
}

// ---------------------------------------------------------------------------
// Kernel 1: emb row norms (fp32), wave per code.
// ---------------------------------------------------------------------------
__global__ void vq_enorm(const float* __restrict__ emb, float* __restrict__ e_norm) {
    int item = blockIdx.x * 4 + (threadIdx.x >> 6);
    int lane = threadIdx.x & 63;
    const float4* s4 = (const float4*)(emb + (size_t)item * D_DIM);
    float4 a = s4[lane];
    float4 b = s4[64 + lane];
    float s = a.x * a.x + a.y * a.y + a.z * a.z + a.w * a.w
            + b.x * b.x + b.y * b.y + b.z * b.z + b.w * b.w;
    #pragma unroll
    for (int off = 32; off > 0; off >>= 1) s += __shfl_down(s, off);
    if (lane == 0) e_norm[item] = s;
}

// ---------------------------------------------------------------------------
// Kernel 2: MFMA split-bf16 distance GEMM + running argmin/sec + flagging.
// ---------------------------------------------------------------------------
__device__ __forceinline__ int kswz(int r) { return (r & 3) ^ ((r >> 2) & 3); }

__global__ __launch_bounds__(512, 2)
void vq_argmin_mfma(const short* __restrict__ Ah_g, const short* __restrict__ Al_g,
                    const short* __restrict__ Bh_g, const short* __restrict__ Bl_g,
                    const float* __restrict__ e_norm,
                    unsigned short* __restrict__ fidx,
                    int* __restrict__ flagcnt, int* __restrict__ flaglist)
{
    __shared__ short smem[24576];   // 48KB: Ah|Al|Bh|Bl
    short* Ah = smem;
    short* Al = smem + 4096;
    short* Bh = smem + 8192;
    short* Bl = smem + 16384;

    const int tid = threadIdx.x;
    const int l   = tid & 63;
    const int wid = tid >> 6;
    const int wr  = wid >> 2;      // 0..1
    const int wc  = wid & 3;       // 0..3
    const int l15 = l & 15;
    const int lhi = l >> 4;
    const int row0 = blockIdx.x * 128;

    float best[16], sec[16];
    int   bidx[16];
    #pragma unroll
    for (int s = 0; s < 16; ++s) { best[s] = FLT_MAX; sec[s] = FLT_MAX; bidx[s] = 0; }

    int offA[4], offB[4];
    #pragma unroll
    for (int m = 0; m < 4; ++m) {
        int r = wr * 64 + m * 16 + l15;
        offA[m] = r * 32 + (lhi ^ kswz(r)) * 8;
    }
    #pragma unroll
    for (int n = 0; n < 4; ++n) {
        int r = wc * 64 + n * 16 + l15;
        offB[n] = r * 32 + (lhi ^ kswz(r)) * 8;
    }

    for (int kt = 0; kt < 16; ++kt) {
        const int cb0 = kt * 256;
        f32x4 acc[4][4];
        #pragma unroll
        for (int m = 0; m < 4; ++m)
            #pragma unroll
            for (int n = 0; n < 4; ++n) acc[m][n] = (f32x4){0.f, 0.f, 0.f, 0.f};

        for (int dt = 0; dt < 16; ++dt) {
            const int k0 = dt * 32;
            __syncthreads();
            {
                int r = tid >> 2, sl = tid & 3;
                size_t go = (size_t)(row0 + r) * D_DIM + k0 + (sl ^ kswz(r)) * 8;
                gld16(Ah_g + go, Ah + tid * 8);
                gld16(Al_g + go, Al + tid * 8);
            }
            #pragma unroll
            for (int jj = 0; jj < 2; ++jj) {
                int c = jj * 512 + tid;
                int r = c >> 2, sl = c & 3;
                size_t go = (size_t)(cb0 + r) * D_DIM + k0 + (sl ^ kswz(r)) * 8;
                gld16(Bh_g + go, Bh + c * 8);
                gld16(Bl_g + go, Bl + c * 8);
            }
            __syncthreads();

            s16x8 ah[4], al[4], bh[4], bl[4];
            #pragma unroll
            for (int m = 0; m < 4; ++m) {
                ah[m] = *(const s16x8*)(Ah + offA[m]);
                al[m] = *(const s16x8*)(Al + offA[m]);
            }
            #pragma unroll
            for (int n = 0; n < 4; ++n) {
                bh[n] = *(const s16x8*)(Bh + offB[n]);
                bl[n] = *(const s16x8*)(Bl + offB[n]);
            }
            #pragma unroll
            for (int m = 0; m < 4; ++m)
                #pragma unroll
                for (int n = 0; n < 4; ++n) {
                    acc[m][n] = __builtin_amdgcn_mfma_f32_16x16x32_bf16(ah[m], bh[n], acc[m][n], 0, 0, 0);
                    acc[m][n] = __builtin_amdgcn_mfma_f32_16x16x32_bf16(ah[m], bl[n], acc[m][n], 0, 0, 0);
                    acc[m][n] = __builtin_amdgcn_mfma_f32_16x16x32_bf16(al[m], bh[n], acc[m][n], 0, 0, 0);
                }
        }

        #pragma unroll
        for (int n = 0; n < 4; ++n) {
            int c = cb0 + wc * 64 + n * 16 + l15;
            float en = e_norm[c];
            #pragma unroll
            for (int m = 0; m < 4; ++m)
                #pragma unroll
                for (int r = 0; r < 4; ++r) {
                    float dv = __fmaf_rn(-2.f, acc[m][n][r], en);
                    int s = m * 4 + r;
                    if (dv < best[s]) { sec[s] = best[s]; best[s] = dv; bidx[s] = c; }
                    else if (dv < sec[s]) sec[s] = dv;
                }
        }
    }

    // intra-wave reduce across the 16 lanes (l15) sharing each row
    #pragma unroll
    for (int s = 0; s < 16; ++s) {
        float v = best[s], sc = sec[s];
        int ix = bidx[s];
        #pragma unroll
        for (int off = 8; off > 0; off >>= 1) {
            float v2 = __shfl_xor(v, off);
            float s2 = __shfl_xor(sc, off);
            int   i2 = __shfl_xor(ix, off);
            float ns = fminf(fminf(sc, s2), fmaxf(v, v2));
            if (v2 < v || (v2 == v && i2 < ix)) { v = v2; ix = i2; }
            sc = ns;
        }
        best[s] = v; sec[s] = sc; bidx[s] = ix;
    }

    // cross-wave merge via LDS (reuse staging area)
    __syncthreads();
    float* mb = (float*)smem;        // [4][128]
    float* ms = mb + 512;
    int*   mi = (int*)(mb + 1024);
    if (l15 == 0) {
        #pragma unroll
        for (int m = 0; m < 4; ++m)
            #pragma unroll
            for (int r = 0; r < 4; ++r) {
                int s = m * 4 + r;
                int rowblk = wr * 64 + m * 16 + lhi * 4 + r;
                mb[wc * 128 + rowblk] = best[s];
                ms[wc * 128 + rowblk] = sec[s];
                mi[wc * 128 + rowblk] = bidx[s];
            }
    }
    __syncthreads();
    if (tid < 128) {
        float B = FLT_MAX, S = FLT_MAX;
        int I = 0;
        #pragma unroll
        for (int w = 0; w < 4; ++w) {
            float b = mb[w * 128 + tid], s = ms[w * 128 + tid];
            int i = mi[w * 128 + tid];
            if (b < B || (b == B && i < I)) { S = fminf(B, s); B = b; I = i; }
            else S = fminf(S, fminf(b, s));
        }
        int row = row0 + tid;
        fidx[row] = (unsigned short)I;
        if (S - B < EPS_GAP) {
            int p = atomicAdd(flagcnt, 1);
            if (p < FLAG_CAP) flaglist[p] = row;
        }
    }
}

// ---------------------------------------------------------------------------
// Kernel 3: flagged-row resolve, 4 rows share each emb sweep.
// ---------------------------------------------------------------------------
#define FIXT 512
#define MAXC 128

__global__ __launch_bounds__(FIXT)
void vq_fix4(const float* __restrict__ lat, const float* __restrict__ emb,
             const int* __restrict__ flagcnt, const int* __restrict__ flaglist,
             unsigned short* __restrict__ fidx)
{
    __shared__ float  xs[4][D_DIM];
    __shared__ double wmin[4][8];
    __shared__ int    ccnt[4];
    __shared__ int    cands[4][MAXC];
    __shared__ float  cd32[4][MAXC];

    const int t    = threadIdx.x;
    const int wave = t >> 6;
    const int lane = t & 63;
    int cnt = *flagcnt;
    if (cnt > FLAG_CAP) cnt = FLAG_CAP;

    for (int g = blockIdx.x; g * 4 < cnt; g += gridDim.x) {
        int rows[4];
        #pragma unroll
        for (int j = 0; j < 4; ++j) {
            int fi = g * 4 + j; if (fi >= cnt) fi = cnt - 1;
            rows[j] = flaglist[fi];
        }
        __syncthreads();
        #pragma unroll
        for (int j = 0; j < 4; ++j) xs[j][t] = lat[(size_t)rows[j] * D_DIM + t];
        if (t < 4) ccnt[t] = 0;
        __syncthreads();

        double xa[4][8];
        #pragma unroll
        for (int j = 0; j < 4; ++j)
            #pragma unroll
            for (int q = 0; q < 8; ++q) xa[j][q] = (double)xs[j][lane * 8 + q];

        double lmin[4] = {DBL_MAX, DBL_MAX, DBL_MAX, DBL_MAX};
        for (int c = wave; c < K_CODES; c += 8) {
            const float4* e4 = (const float4*)(emb + (size_t)c * D_DIM);
            float4 ea = e4[lane * 2], eb = e4[lane * 2 + 1];
            double ev[8] = {ea.x, ea.y, ea.z, ea.w, eb.x, eb.y, eb.z, eb.w};
            #pragma unroll
            for (int j = 0; j < 4; ++j) {
                double s = 0.0;
                #pragma unroll
                for (int q = 0; q < 8; ++q) { double d = xa[j][q] - ev[q]; s = fma(d, d, s); }
                #pragma unroll
                for (int off = 32; off > 0; off >>= 1) s += __shfl_xor(s, off);
                if (s < lmin[j]) lmin[j] = s;
            }
        }
        if (lane == 0)
            #pragma unroll
            for (int j = 0; j < 4; ++j) wmin[j][wave] = lmin[j];
        __syncthreads();

        float thr[4];
        #pragma unroll
        for (int j = 0; j < 4; ++j) {
            double gm = wmin[j][0];
            #pragma unroll
            for (int w = 1; w < 8; ++w) gm = fmin(gm, wmin[j][w]);
            thr[j] = (float)(gm + EPS_CAND);
        }

        for (int c = wave; c < K_CODES; c += 8) {
            const float4* e4 = (const float4*)(emb + (size_t)c * D_DIM);
            float4 ea = e4[lane * 2], eb = e4[lane * 2 + 1];
            double ev[8] = {ea.x, ea.y, ea.z, ea.w, eb.x, eb.y, eb.z, eb.w};
            #pragma unroll
            for (int j = 0; j < 4; ++j) {
                double s = 0.0;
                #pragma unroll
                for (int q = 0; q < 8; ++q) { double d = xa[j][q] - ev[q]; s = fma(d, d, s); }
                #pragma unroll
                for (int off = 32; off > 0; off >>= 1) s += __shfl_xor(s, off);
                if (lane == 0 && (float)s < thr[j]) {
                    int p = atomicAdd(&ccnt[j], 1);
                    if (p < MAXC) cands[j][p] = c;
                }
            }
        }
        __syncthreads();

        {
            int j = t >> 7, ci = t & 127;
            int nc = ccnt[j] < MAXC ? ccnt[j] : MAXC;
            if (ci < nc) {
                int c = cands[j][ci];
                const float* e = emb + (size_t)c * D_DIM;
                float t1 = np_sum512_sq(xs[j]);
                float t2 = np_sum512_sq(e);
                float dot = 0.f;
                for (int k = 0; k < D_DIM; ++k)
                    dot = __fmaf_rn(xs[j][k], e[k], dot);
                cd32[j][ci] = __fsub_rn(__fadd_rn(t1, t2), __fmul_rn(2.f, dot));
            }
        }
        __syncthreads();
        if ((t & 127) == 0) {
            int j = t >> 7;
            int nc = ccnt[j] < MAXC ? ccnt[j] : MAXC;
            float bv = cd32[j][0]; int bx = cands[j][0];
            for (int w = 1; w < nc; ++w)
                if (cd32[j][w] < bv || (cd32[j][w] == bv && cands[j][w] < bx)) {
                    bv = cd32[j][w]; bx = cands[j][w];
                }
            fidx[rows[j]] = (unsigned short)bx;
        }
        __syncthreads();
    }
}

// ---------------------------------------------------------------------------
// Kernel 4: gather quantized rows, per-row MSE partial, histogram.
// ---------------------------------------------------------------------------
__global__ void vq_gather(const float* __restrict__ lat, const float* __restrict__ emb,
                          const unsigned short* __restrict__ fidx,
                          float* __restrict__ out_q,
                          float* __restrict__ rowpart, int* __restrict__ hist) {
    int row  = blockIdx.x * 4 + (threadIdx.x >> 6);
    int lane = threadIdx.x & 63;
    int idx  = fidx[row];

    if (lane == 0) atomicAdd(&hist[idx], 1);

    const float4* e4 = (const float4*)(emb + (size_t)idx * D_DIM);
    const float4* x4 = (const float4*)(lat + (size_t)row * D_DIM);
    float4*       q4 = (float4*)(out_q + (size_t)row * D_DIM);

    float s = 0.f;
    #pragma unroll
    for (int i = 0; i < 2; ++i) {
        float4 e = e4[i * 64 + lane];
        float4 x = x4[i * 64 + lane];
        q4[i * 64 + lane] = e;
        float dx = e.x - x.x, dy = e.y - x.y, dz = e.z - x.z, dw = e.w - x.w;
        s += dx * dx + dy * dy + dz * dz + dw * dw;
    }
    #pragma unroll
    for (int off = 32; off > 0; off >>= 1) s += __shfl_down(s, off);
    if (lane == 0) rowpart[row] = s;
}

// ---------------------------------------------------------------------------
// Kernel 5: final reductions (loss, perplexity).
// ---------------------------------------------------------------------------
__global__ void vq_finalize(const float* __restrict__ rowpart, const int* __restrict__ hist,
                            float* __restrict__ out_loss, float* __restrict__ out_perp) {
    __shared__ float sdata[256];
    int t = threadIdx.x;

    float s = 0.f;
    for (int i = t; i < N_ROWS; i += 256) s += rowpart[i];
    sdata[t] = s;
    __syncthreads();
    for (int st = 128; st > 0; st >>= 1) {
        if (t < st) sdata[t] += sdata[t + st];
        __syncthreads();
    }
    if (t == 0) out_loss[0] = 1.05f * (sdata[0] / ((float)N_ROWS * (float)D_DIM));
    __syncthreads();

    float p = 0.f;
    for (int i = t; i < K_CODES; i += 256) {
        float pr = (float)hist[i] / (float)N_ROWS;
        p += pr * logf(pr + 1e-10f);
    }
    sdata[t] = p;
    __syncthreads();
    for (int st = 128; st > 0; st >>= 1) {
        if (t < st) sdata[t] += sdata[t + st];
        __syncthreads();
    }
    if (t == 0) out_perp[0] = expf(-sdata[0]);
}

// ---------------------------------------------------------------------------
// Kernel 6: fidx u16 -> out_inds float.
// ---------------------------------------------------------------------------
__global__ void vq_inds(const unsigned short* __restrict__ fidx, float* __restrict__ out_inds) {
    int i = blockIdx.x * 1024 + threadIdx.x;
    out_inds[i] = (float)fidx[i];
}

// ---------------------------------------------------------------------------
extern "C" void kernel_launch(void* const* d_in, const int* in_sizes, int n_in,
                              void* d_out, int out_size, void* d_ws, size_t ws_size,
                              hipStream_t stream) {
    const float* lat = (const float*)d_in[0];
    const float* emb = (const float*)d_in[1];
    float* ob = (float*)d_out;

    short* emb_hi = (short*)(ob + 0);
    short* emb_lo = (short*)(ob + 1048576);
    short* lat_hi = (short*)(ob + 2097152);
    short* lat_lo = (short*)(ob + 10485760);
    float* e_norm = ob + 18874368;
    int*   flagcnt  = (int*)(ob + 18878464);
    int*   flaglist = (int*)(ob + 18878465);
    unsigned short* fidx = (unsigned short*)(ob + 18890496);
    int*   hist    = (int*)(ob + 16777220);
    float* rowpart = ob + 16781316;

    float* out_q    = ob;
    float* out_loss = ob + 16777216;
    float* out_inds = ob + 16777217;
    float* out_emb  = ob + 16809985;
    float* out_perp = ob + 18907137;

    // flagcnt lives in the clean tail (never touched by vq_convert) -> zero now.
    hipMemsetAsync(flagcnt, 0, sizeof(int), stream);

    vq_convert<<<dim3(9216), dim3(256), 0, stream>>>(lat, emb, lat_hi, lat_lo, emb_hi, emb_lo);
    vq_enorm<<<dim3(1024), dim3(256), 0, stream>>>(emb, e_norm);

    vq_argmin_mfma<<<dim3(256), dim3(512), 0, stream>>>(lat_hi, lat_lo, emb_hi, emb_lo,
                                                        e_norm, fidx, flagcnt, flaglist);

    // hist overlaps lat_lo -> zero it only AFTER the argmin consumed lat_lo.
    hipMemsetAsync(hist, 0, K_CODES * sizeof(int), stream);

    vq_fix4<<<dim3(256), dim3(FIXT), 0, stream>>>(lat, emb, flagcnt, flaglist, fidx);

    vq_gather<<<dim3(N_ROWS / 4), dim3(256), 0, stream>>>(lat, emb, fidx, out_q, rowpart, hist);

    vq_finalize<<<dim3(1), dim3(256), 0, stream>>>(rowpart, hist, out_loss, out_perp);

    vq_inds<<<dim3(32), dim3(1024), 0, stream>>>(fidx, out_inds);

    hipMemcpyAsync(out_emb, emb, (size_t)K_CODES * D_DIM * sizeof(float),
                   hipMemcpyDeviceToDevice, stream);
}

// Round 9
// 1168.841 us; speedup vs baseline: 7.1319x; 1.9257x over previous
//
#include <hip/hip_runtime.h>
#include <cfloat>
#include <cmath>
#include <climits>
#include <cstdint>

// Problem constants
#define N_ROWS   32768
#define D_DIM    512
#define K_CODES  4096

#define EPS_GAP  0.008f     // MFMA-path gap below which we re-check via np-emulation
#define CAND_WIN 0.02f      // fp32-screen window that provably contains the np-argmin
#define FLAG_CAP 12000

typedef short s16x8 __attribute__((ext_vector_type(8)));
typedef float f32x4 __attribute__((ext_vector_type(4)));

// ---------------------------------------------------------------------------
// Flat scratch layout in d_out (float indices).
//   emb_hi  [0, 1048576)           bf16 bits (4096x512 shorts)
//   emb_lo  [1048576, 2097152)
//   lat_hi  [2097152, 10485760)    (32768x512 shorts)
//   lat_lo  [10485760, 18874368)
//   e_norm  [18874368, 18878464)   -- clean tail (no overlap with splits)
//   flagcnt [18878464]
//   flaglist[18878465, 18890465)
//   fidx    u16 at [18890496, 18906880)
//   hist    [16777220, 16781316)   INSIDE lat_lo span -> zeroed only AFTER
//                                  vq_argmin_mfma (lat_lo dead)!
//   rowpart [16781316, 16814084)   (same zone; fully written post-argmin)
// Outputs: out_q [0,16777216) loss[16777216] inds[16777217,16809985)
//          emb  [16809985,18907137) perp[18907137]
// ---------------------------------------------------------------------------

__device__ __forceinline__ short f2bf_rne(float x) {
    unsigned u = __float_as_uint(x);
    unsigned r = (u + 0x7fffu + ((u >> 16) & 1u)) >> 16;
    return (short)r;
}
__device__ __forceinline__ float bf2f(short b) {
    return __uint_as_float(((unsigned)(unsigned short)b) << 16);
}

__device__ __forceinline__ void gld16(const short* g, short* l) {
    __builtin_amdgcn_global_load_lds(
        reinterpret_cast<const __attribute__((address_space(1))) unsigned int*>(
            reinterpret_cast<uintptr_t>(g)),
        reinterpret_cast<__attribute__((address_space(3))) unsigned int*>(
            (unsigned int)(reinterpret_cast<uintptr_t>(l))),
        16, 0, 0);
}

// ---------------------------------------------------------------------------
// numpy fp32 pairwise-sum emulation (AVX512/GCC path) -- unchanged, proven.
// ---------------------------------------------------------------------------
__device__ __forceinline__ float np_block128_sq(const float* p) {
    float P[16];
    #pragma unroll
    for (int l = 0; l < 16; ++l) {
        float s0 = __fmul_rn(p[0 * 16 + l], p[0 * 16 + l]);
        float s1 = __fmul_rn(p[1 * 16 + l], p[1 * 16 + l]);
        float s2 = __fmul_rn(p[2 * 16 + l], p[2 * 16 + l]);
        float s3 = __fmul_rn(p[3 * 16 + l], p[3 * 16 + l]);
        float s4 = __fmul_rn(p[4 * 16 + l], p[4 * 16 + l]);
        float s5 = __fmul_rn(p[5 * 16 + l], p[5 * 16 + l]);
        float s6 = __fmul_rn(p[6 * 16 + l], p[6 * 16 + l]);
        float s7 = __fmul_rn(p[7 * 16 + l], p[7 * 16 + l]);
        float a01 = __fadd_rn(s0, s1);
        float a23 = __fadd_rn(s2, s3);
        float a45 = __fadd_rn(s4, s5);
        float a67 = __fadd_rn(s6, s7);
        P[l] = __fadd_rn(__fadd_rn(a01, a23), __fadd_rn(a45, a67));
    }
    float T3[8];
    #pragma unroll
    for (int k = 0; k < 8; ++k) T3[k] = __fadd_rn(P[k], P[k + 8]);
    float T6[4];
    #pragma unroll
    for (int k = 0; k < 4; ++k) T6[k] = __fadd_rn(T3[k], T3[k + 4]);
    return __fadd_rn(__fadd_rn(__fadd_rn(T6[0], T6[1]), T6[2]), T6[3]);
}
__device__ __forceinline__ float np_sum512_sq(const float* p) {
    float B0 = np_block128_sq(p);
    float B1 = np_block128_sq(p + 128);
    float B2 = np_block128_sq(p + 256);
    float B3 = np_block128_sq(p + 384);
    return __fadd_rn(__fadd_rn(B0, B1), __fadd_rn(B2, B3));
}

// ---------------------------------------------------------------------------
// Kernel 0: split fp32 -> bf16 hi/lo for lat and emb.  8 elems per thread.
// ---------------------------------------------------------------------------
__global__ void vq_convert(const float* __restrict__ lat, const float* __restrict__ emb,
                           short* __restrict__ lat_hi, short* __restrict__ lat_lo,
                           short* __restrict__ emb_hi, short* __restrict__ emb_lo) {
    int i = blockIdx.x * 256 + threadIdx.x;
    const float* src; short *dh, *dl; size_t base;
    if (i < 2097152) { src = lat; dh = lat_hi; dl = lat_lo; base = (size_t)i * 8; }
    else             { src = emb; dh = emb_hi; dl = emb_lo; base = (size_t)(i - 2097152) * 8; }
    float4 a = *(const float4*)(src + base);
    float4 b = *(const float4*)(src + base + 4);
    float x[8] = {a.x, a.y, a.z, a.w, b.x, b.y, b.z, b.w};
    s16x8 hv, lv;
    #pragma unroll
    for (int j = 0; j < 8; ++j) {
        short h = f2bf_rne(x[j]);
        hv[j] = h;
        lv[j] = f2bf_rne(x[j] - bf2f(h));
    }
    *(s16x8*)(dh + base) = hv;
    *(s16x8*)(dl + base) = lv;
}

// ---------------------------------------------------------------------------
// Kernel 1: emb row norms (fp32), wave per code.
// ---------------------------------------------------------------------------
__global__ void vq_enorm(const float* __restrict__ emb, float* __restrict__ e_norm) {
    int item = blockIdx.x * 4 + (threadIdx.x >> 6);
    int lane = threadIdx.x & 63;
    const float4* s4 = (const float4*)(emb + (size_t)item * D_DIM);
    float4 a = s4[lane];
    float4 b = s4[64 + lane];
    float s = a.x * a.x + a.y * a.y + a.z * a.z + a.w * a.w
            + b.x * b.x + b.y * b.y + b.z * b.z + b.w * b.w;
    #pragma unroll
    for (int off = 32; off > 0; off >>= 1) s += __shfl_down(s, off);
    if (lane == 0) e_norm[item] = s;
}

// ---------------------------------------------------------------------------
// Kernel 2: MFMA split-bf16 distance GEMM + running argmin/sec + flagging.
// (unchanged from the passing round)
// ---------------------------------------------------------------------------
__device__ __forceinline__ int kswz(int r) { return (r & 3) ^ ((r >> 2) & 3); }

__global__ __launch_bounds__(512, 2)
void vq_argmin_mfma(const short* __restrict__ Ah_g, const short* __restrict__ Al_g,
                    const short* __restrict__ Bh_g, const short* __restrict__ Bl_g,
                    const float* __restrict__ e_norm,
                    unsigned short* __restrict__ fidx,
                    int* __restrict__ flagcnt, int* __restrict__ flaglist)
{
    __shared__ short smem[24576];   // 48KB: Ah|Al|Bh|Bl
    short* Ah = smem;
    short* Al = smem + 4096;
    short* Bh = smem + 8192;
    short* Bl = smem + 16384;

    const int tid = threadIdx.x;
    const int l   = tid & 63;
    const int wid = tid >> 6;
    const int wr  = wid >> 2;
    const int wc  = wid & 3;
    const int l15 = l & 15;
    const int lhi = l >> 4;
    const int row0 = blockIdx.x * 128;

    float best[16], sec[16];
    int   bidx[16];
    #pragma unroll
    for (int s = 0; s < 16; ++s) { best[s] = FLT_MAX; sec[s] = FLT_MAX; bidx[s] = 0; }

    int offA[4], offB[4];
    #pragma unroll
    for (int m = 0; m < 4; ++m) {
        int r = wr * 64 + m * 16 + l15;
        offA[m] = r * 32 + (lhi ^ kswz(r)) * 8;
    }
    #pragma unroll
    for (int n = 0; n < 4; ++n) {
        int r = wc * 64 + n * 16 + l15;
        offB[n] = r * 32 + (lhi ^ kswz(r)) * 8;
    }

    for (int kt = 0; kt < 16; ++kt) {
        const int cb0 = kt * 256;
        f32x4 acc[4][4];
        #pragma unroll
        for (int m = 0; m < 4; ++m)
            #pragma unroll
            for (int n = 0; n < 4; ++n) acc[m][n] = (f32x4){0.f, 0.f, 0.f, 0.f};

        for (int dt = 0; dt < 16; ++dt) {
            const int k0 = dt * 32;
            __syncthreads();
            {
                int r = tid >> 2, sl = tid & 3;
                size_t go = (size_t)(row0 + r) * D_DIM + k0 + (sl ^ kswz(r)) * 8;
                gld16(Ah_g + go, Ah + tid * 8);
                gld16(Al_g + go, Al + tid * 8);
            }
            #pragma unroll
            for (int jj = 0; jj < 2; ++jj) {
                int c = jj * 512 + tid;
                int r = c >> 2, sl = c & 3;
                size_t go = (size_t)(cb0 + r) * D_DIM + k0 + (sl ^ kswz(r)) * 8;
                gld16(Bh_g + go, Bh + c * 8);
                gld16(Bl_g + go, Bl + c * 8);
            }
            __syncthreads();

            s16x8 ah[4], al[4], bh[4], bl[4];
            #pragma unroll
            for (int m = 0; m < 4; ++m) {
                ah[m] = *(const s16x8*)(Ah + offA[m]);
                al[m] = *(const s16x8*)(Al + offA[m]);
            }
            #pragma unroll
            for (int n = 0; n < 4; ++n) {
                bh[n] = *(const s16x8*)(Bh + offB[n]);
                bl[n] = *(const s16x8*)(Bl + offB[n]);
            }
            #pragma unroll
            for (int m = 0; m < 4; ++m)
                #pragma unroll
                for (int n = 0; n < 4; ++n) {
                    acc[m][n] = __builtin_amdgcn_mfma_f32_16x16x32_bf16(ah[m], bh[n], acc[m][n], 0, 0, 0);
                    acc[m][n] = __builtin_amdgcn_mfma_f32_16x16x32_bf16(ah[m], bl[n], acc[m][n], 0, 0, 0);
                    acc[m][n] = __builtin_amdgcn_mfma_f32_16x16x32_bf16(al[m], bh[n], acc[m][n], 0, 0, 0);
                }
        }

        #pragma unroll
        for (int n = 0; n < 4; ++n) {
            int c = cb0 + wc * 64 + n * 16 + l15;
            float en = e_norm[c];
            #pragma unroll
            for (int m = 0; m < 4; ++m)
                #pragma unroll
                for (int r = 0; r < 4; ++r) {
                    float dv = __fmaf_rn(-2.f, acc[m][n][r], en);
                    int s = m * 4 + r;
                    if (dv < best[s]) { sec[s] = best[s]; best[s] = dv; bidx[s] = c; }
                    else if (dv < sec[s]) sec[s] = dv;
                }
        }
    }

    #pragma unroll
    for (int s = 0; s < 16; ++s) {
        float v = best[s], sc = sec[s];
        int ix = bidx[s];
        #pragma unroll
        for (int off = 8; off > 0; off >>= 1) {
            float v2 = __shfl_xor(v, off);
            float s2 = __shfl_xor(sc, off);
            int   i2 = __shfl_xor(ix, off);
            float ns = fminf(fminf(sc, s2), fmaxf(v, v2));
            if (v2 < v || (v2 == v && i2 < ix)) { v = v2; ix = i2; }
            sc = ns;
        }
        best[s] = v; sec[s] = sc; bidx[s] = ix;
    }

    __syncthreads();
    float* mb = (float*)smem;
    float* ms = mb + 512;
    int*   mi = (int*)(mb + 1024);
    if (l15 == 0) {
        #pragma unroll
        for (int m = 0; m < 4; ++m)
            #pragma unroll
            for (int r = 0; r < 4; ++r) {
                int s = m * 4 + r;
                int rowblk = wr * 64 + m * 16 + lhi * 4 + r;
                mb[wc * 128 + rowblk] = best[s];
                ms[wc * 128 + rowblk] = sec[s];
                mi[wc * 128 + rowblk] = bidx[s];
            }
    }
    __syncthreads();
    if (tid < 128) {
        float B = FLT_MAX, S = FLT_MAX;
        int I = 0;
        #pragma unroll
        for (int w = 0; w < 4; ++w) {
            float b = mb[w * 128 + tid], s = ms[w * 128 + tid];
            int i = mi[w * 128 + tid];
            if (b < B || (b == B && i < I)) { S = fminf(B, s); B = b; I = i; }
            else S = fminf(S, fminf(b, s));
        }
        int row = row0 + tid;
        fidx[row] = (unsigned short)I;
        if (S - B < EPS_GAP) {
            int p = atomicAdd(flagcnt, 1);
            if (p < FLAG_CAP) flaglist[p] = row;
        }
    }
}

// ---------------------------------------------------------------------------
// Kernel 3 (rewritten): flagged-row resolve, ONE row per block, ONE fp32
// screening sweep (wave-per-code, coalesced), then bit-exact np eval on the
// tiny candidate set.
//  - screen: d_s[c] = sum (x-e)^2, lane partials (8 terms) + 6-level tree;
//    |d_s - d_exact| <= ~2e-4.
//  - |d_np - d_exact| <= ~1.6e-3  =>  window 0.02 provably contains np-argmin.
// ---------------------------------------------------------------------------
#define FIXT 512
#define MAXC 128

__global__ __launch_bounds__(FIXT)
void vq_fixrow(const float* __restrict__ lat, const float* __restrict__ emb,
               const int* __restrict__ flagcnt, const int* __restrict__ flaglist,
               unsigned short* __restrict__ fidx)
{
    __shared__ float xs[D_DIM];
    __shared__ float dall[K_CODES];     // 16 KB
    __shared__ float wmin_s[8];
    __shared__ int   ccnt;
    __shared__ int   cands[MAXC];
    __shared__ float cd32[MAXC];

    const int t    = threadIdx.x;
    const int wave = t >> 6;
    const int lane = t & 63;
    int cnt = *flagcnt;
    if (cnt > FLAG_CAP) cnt = FLAG_CAP;

    for (int f = blockIdx.x; f < cnt; f += gridDim.x) {
        const int row = flaglist[f];
        __syncthreads();   // protect LDS reuse across row iterations
        xs[t] = lat[(size_t)row * D_DIM + t];
        if (t == 0) ccnt = 0;
        __syncthreads();

        float x8[8];
        #pragma unroll
        for (int q = 0; q < 8; ++q) x8[q] = xs[lane * 8 + q];

        // ---- fp32 screening sweep: wave per code, 512 codes per wave ----
        float lmin = FLT_MAX;
        for (int c = wave; c < K_CODES; c += 8) {
            const float4* e4 = (const float4*)(emb + (size_t)c * D_DIM);
            float4 ea = e4[lane * 2];
            float4 eb = e4[lane * 2 + 1];
            float d0 = x8[0] - ea.x, d1 = x8[1] - ea.y;
            float d2 = x8[2] - ea.z, d3 = x8[3] - ea.w;
            float d4 = x8[4] - eb.x, d5 = x8[5] - eb.y;
            float d6 = x8[6] - eb.z, d7 = x8[7] - eb.w;
            float sA = __fmaf_rn(d0, d0, __fmaf_rn(d1, d1, __fmaf_rn(d2, d2, d3 * d3)));
            float sB = __fmaf_rn(d4, d4, __fmaf_rn(d5, d5, __fmaf_rn(d6, d6, d7 * d7)));
            float s = sA + sB;
            #pragma unroll
            for (int off = 32; off > 0; off >>= 1) s += __shfl_xor(s, off);
            if (lane == 0) dall[c] = s;
            lmin = fminf(lmin, s);
        }
        if (lane == 0) wmin_s[wave] = lmin;
        __syncthreads();

        float gmin = wmin_s[0];
        #pragma unroll
        for (int w = 1; w < 8; ++w) gmin = fminf(gmin, wmin_s[w]);
        const float thr = gmin + CAND_WIN;

        for (int c = t; c < K_CODES; c += FIXT) {
            if (dall[c] < thr) {
                int p = atomicAdd(&ccnt, 1);
                if (p < MAXC) cands[p] = c;
            }
        }
        __syncthreads();

        // ---- bit-exact np eval on candidates ----
        int nc = ccnt < MAXC ? ccnt : MAXC;
        if (t < nc) {
            int c = cands[t];
            const float* e = emb + (size_t)c * D_DIM;
            float t1 = np_sum512_sq(xs);
            float t2 = np_sum512_sq(e);
            float dot = 0.f;
            for (int k = 0; k < D_DIM; ++k)
                dot = __fmaf_rn(xs[k], e[k], dot);     // sequential, BLAS order
            cd32[t] = __fsub_rn(__fadd_rn(t1, t2), __fmul_rn(2.f, dot));
        }
        __syncthreads();

        if (t == 0) {
            float bv = cd32[0]; int bx = cands[0];
            for (int w = 1; w < nc; ++w)
                if (cd32[w] < bv || (cd32[w] == bv && cands[w] < bx)) {
                    bv = cd32[w]; bx = cands[w];
                }
            fidx[row] = (unsigned short)bx;
        }
    }
}

// ---------------------------------------------------------------------------
// Kernel 4: gather quantized rows, per-row MSE partial, histogram.
// ---------------------------------------------------------------------------
__global__ void vq_gather(const float* __restrict__ lat, const float* __restrict__ emb,
                          const unsigned short* __restrict__ fidx,
                          float* __restrict__ out_q,
                          float* __restrict__ rowpart, int* __restrict__ hist) {
    int row  = blockIdx.x * 4 + (threadIdx.x >> 6);
    int lane = threadIdx.x & 63;
    int idx  = fidx[row];

    if (lane == 0) atomicAdd(&hist[idx], 1);

    const float4* e4 = (const float4*)(emb + (size_t)idx * D_DIM);
    const float4* x4 = (const float4*)(lat + (size_t)row * D_DIM);
    float4*       q4 = (float4*)(out_q + (size_t)row * D_DIM);

    float s = 0.f;
    #pragma unroll
    for (int i = 0; i < 2; ++i) {
        float4 e = e4[i * 64 + lane];
        float4 x = x4[i * 64 + lane];
        q4[i * 64 + lane] = e;
        float dx = e.x - x.x, dy = e.y - x.y, dz = e.z - x.z, dw = e.w - x.w;
        s += dx * dx + dy * dy + dz * dz + dw * dw;
    }
    #pragma unroll
    for (int off = 32; off > 0; off >>= 1) s += __shfl_down(s, off);
    if (lane == 0) rowpart[row] = s;
}

// ---------------------------------------------------------------------------
// Kernel 5: final reductions (loss, perplexity).
// ---------------------------------------------------------------------------
__global__ void vq_finalize(const float* __restrict__ rowpart, const int* __restrict__ hist,
                            float* __restrict__ out_loss, float* __restrict__ out_perp) {
    __shared__ float sdata[256];
    int t = threadIdx.x;

    float s = 0.f;
    for (int i = t; i < N_ROWS; i += 256) s += rowpart[i];
    sdata[t] = s;
    __syncthreads();
    for (int st = 128; st > 0; st >>= 1) {
        if (t < st) sdata[t] += sdata[t + st];
        __syncthreads();
    }
    if (t == 0) out_loss[0] = 1.05f * (sdata[0] / ((float)N_ROWS * (float)D_DIM));
    __syncthreads();

    float p = 0.f;
    for (int i = t; i < K_CODES; i += 256) {
        float pr = (float)hist[i] / (float)N_ROWS;
        p += pr * logf(pr + 1e-10f);
    }
    sdata[t] = p;
    __syncthreads();
    for (int st = 128; st > 0; st >>= 1) {
        if (t < st) sdata[t] += sdata[t + st];
        __syncthreads();
    }
    if (t == 0) out_perp[0] = expf(-sdata[0]);
}

// ---------------------------------------------------------------------------
// Kernel 6: fidx u16 -> out_inds float.
// ---------------------------------------------------------------------------
__global__ void vq_inds(const unsigned short* __restrict__ fidx, float* __restrict__ out_inds) {
    int i = blockIdx.x * 1024 + threadIdx.x;
    out_inds[i] = (float)fidx[i];
}

// ---------------------------------------------------------------------------
extern "C" void kernel_launch(void* const* d_in, const int* in_sizes, int n_in,
                              void* d_out, int out_size, void* d_ws, size_t ws_size,
                              hipStream_t stream) {
    const float* lat = (const float*)d_in[0];
    const float* emb = (const float*)d_in[1];
    float* ob = (float*)d_out;

    short* emb_hi = (short*)(ob + 0);
    short* emb_lo = (short*)(ob + 1048576);
    short* lat_hi = (short*)(ob + 2097152);
    short* lat_lo = (short*)(ob + 10485760);
    float* e_norm = ob + 18874368;
    int*   flagcnt  = (int*)(ob + 18878464);
    int*   flaglist = (int*)(ob + 18878465);
    unsigned short* fidx = (unsigned short*)(ob + 18890496);
    int*   hist    = (int*)(ob + 16777220);
    float* rowpart = ob + 16781316;

    float* out_q    = ob;
    float* out_loss = ob + 16777216;
    float* out_inds = ob + 16777217;
    float* out_emb  = ob + 16809985;
    float* out_perp = ob + 18907137;

    // flagcnt lives in the clean tail (never touched by vq_convert) -> zero now.
    hipMemsetAsync(flagcnt, 0, sizeof(int), stream);

    vq_convert<<<dim3(9216), dim3(256), 0, stream>>>(lat, emb, lat_hi, lat_lo, emb_hi, emb_lo);
    vq_enorm<<<dim3(1024), dim3(256), 0, stream>>>(emb, e_norm);

    vq_argmin_mfma<<<dim3(256), dim3(512), 0, stream>>>(lat_hi, lat_lo, emb_hi, emb_lo,
                                                        e_norm, fidx, flagcnt, flaglist);

    // hist overlaps lat_lo -> zero it only AFTER the argmin consumed lat_lo.
    hipMemsetAsync(hist, 0, K_CODES * sizeof(int), stream);

    vq_fixrow<<<dim3(512), dim3(FIXT), 0, stream>>>(lat, emb, flagcnt, flaglist, fidx);

    vq_gather<<<dim3(N_ROWS / 4), dim3(256), 0, stream>>>(lat, emb, fidx, out_q, rowpart, hist);

    vq_finalize<<<dim3(1), dim3(256), 0, stream>>>(rowpart, hist, out_loss, out_perp);

    vq_inds<<<dim3(32), dim3(1024), 0, stream>>>(fidx, out_inds);

    hipMemcpyAsync(out_emb, emb, (size_t)K_CODES * D_DIM * sizeof(float),
                   hipMemcpyDeviceToDevice, stream);
}